// Round 1
// 3208.775 us; speedup vs baseline: 1.9865x; 1.9865x over previous
//
#include <hip/hip_runtime.h>
#include <math.h>

#define B_  2048
#define I_  512
#define H_  512
#define L_  32
#define D_  1024
#define O_  512
#define H4_ 2048
#define KC  32

typedef _Float16 f16x8 __attribute__((ext_vector_type(8)));
typedef _Float16 f16x4 __attribute__((ext_vector_type(4)));
typedef float    f32x4 __attribute__((ext_vector_type(4)));

#define SPLIT_S  1024.0f
#define SPLIT_RS 0.0009765625f   /* 1/1024 */

// ---------------------------------------------------------------------------
// Generic fp32 GEMM (kept for one-time GEMMs: cx0, P_enc, P_dec, recon).
// C[M,N] = A[M,K] @ W[N,K]^T (+ bias). Tile 64x64, 256 thr, 4x4/thread.
// ---------------------------------------------------------------------------
__global__ __launch_bounds__(256) void gemm_atb(
    const float* __restrict__ A, const float* __restrict__ W,
    const float* __restrict__ bias, float* __restrict__ C, int ldc,
    float* __restrict__ C2, int ldc2,
    int M, int N, int K)
{
    __shared__ __align__(16) float As[KC][68];
    __shared__ __align__(16) float Ws[KC][68];
    const int tx = threadIdx.x & 15, ty = threadIdx.x >> 4;
    const int m0 = blockIdx.y * 64, n0 = blockIdx.x * 64;
    float acc[4][4] = {};

    for (int k0 = 0; k0 < K; k0 += KC) {
#pragma unroll
        for (int p = 0; p < 2; ++p) {
            int q = threadIdx.x + 256 * p;
            int r = q >> 3, c = q & 7;
            float4 va = *reinterpret_cast<const float4*>(
                &A[(long long)(m0 + r) * K + k0 + c * 4]);
            As[c * 4 + 0][r] = va.x; As[c * 4 + 1][r] = va.y;
            As[c * 4 + 2][r] = va.z; As[c * 4 + 3][r] = va.w;
            float4 vw = *reinterpret_cast<const float4*>(
                &W[(long long)(n0 + r) * K + k0 + c * 4]);
            Ws[c * 4 + 0][r] = vw.x; Ws[c * 4 + 1][r] = vw.y;
            Ws[c * 4 + 2][r] = vw.z; Ws[c * 4 + 3][r] = vw.w;
        }
        __syncthreads();
#pragma unroll
        for (int kk = 0; kk < KC; ++kk) {
            float4 a = *reinterpret_cast<const float4*>(&As[kk][ty * 4]);
            float4 w = *reinterpret_cast<const float4*>(&Ws[kk][tx * 4]);
            float av[4] = {a.x, a.y, a.z, a.w};
            float wv[4] = {w.x, w.y, w.z, w.w};
#pragma unroll
            for (int i = 0; i < 4; ++i)
#pragma unroll
                for (int j = 0; j < 4; ++j)
                    acc[i][j] = fmaf(av[i], wv[j], acc[i][j]);
        }
        __syncthreads();
    }

#pragma unroll
    for (int i = 0; i < 4; ++i) {
        int m = m0 + ty * 4 + i;
        int n = n0 + tx * 4;
        float4 out;
        out.x = acc[i][0]; out.y = acc[i][1]; out.z = acc[i][2]; out.w = acc[i][3];
        if (bias) {
            out.x += bias[n + 0]; out.y += bias[n + 1];
            out.z += bias[n + 2]; out.w += bias[n + 3];
        }
        *reinterpret_cast<float4*>(&C[(long long)m * ldc + n]) = out;
        if (C2)
            *reinterpret_cast<float4*>(&C2[(long long)m * ldc2 + n]) = out;
    }
}

// ---------------------------------------------------------------------------
// Split fp32 -> scaled fp16 pair:  x ~= x1 + x2/1024  (error ~2^-22 |x|).
// ---------------------------------------------------------------------------
__global__ __launch_bounds__(256) void split_f16(
    const float* __restrict__ src, _Float16* __restrict__ d1,
    _Float16* __restrict__ d2, int n4)
{
    int i = blockIdx.x * 256 + threadIdx.x;
    if (i >= n4) return;
    float4 v = reinterpret_cast<const float4*>(src)[i];
    float vv[4] = {v.x, v.y, v.z, v.w};
    f16x4 o1, o2;
#pragma unroll
    for (int j = 0; j < 4; ++j) {
        _Float16 hh = (_Float16)vv[j];
        o1[j] = hh;
        o2[j] = (_Float16)((vv[j] - (float)hh) * SPLIT_S);
    }
    *reinterpret_cast<f16x4*>(d1 + 4 * i) = o1;
    *reinterpret_cast<f16x4*>(d2 + 4 * i) = o2;
}

// ---------------------------------------------------------------------------
// Fused MFMA LSTM step (split-fp16 GEMM, fp32-grade accuracy):
//   gates = hx @ Whh^T + (bih+bhh) + P[m_prev[b]] ; cell update in epilogue.
// Block: 128 batch rows x 32 h (=128 gate-major cols: c = hh*64+g*16+hl so
// each lane owns all 4 gates of its (b,h) -> shuffle-free epilogue).
// 512 threads = 8 waves (4 m x 2 n), wave tile 32x64, 16x16x32 f16 MFMA,
// BK=64, LDS rows padded to 72 halfs (144B: 16B-aligned, conflict-free).
// Writes cx (in place), hx split pair, and optionally fp32 hx.
// ---------------------------------------------------------------------------
__global__ __launch_bounds__(512) void lstm_step_mfma(
    const _Float16* __restrict__ hx1, const _Float16* __restrict__ hx2,
    float* __restrict__ cx,
    const _Float16* __restrict__ W1, const _Float16* __restrict__ W2, // [4H][H]
    const float* __restrict__ P,      // [D][4H] gather table (fp32)
    const int* __restrict__ m_prev,   // [B] or nullptr
    const float* __restrict__ bih, const float* __restrict__ bhh,
    _Float16* __restrict__ ho1, _Float16* __restrict__ ho2,
    float* __restrict__ hof)          // fp32 hx out (nullptr to skip)
{
    __shared__ __align__(16) _Float16 As1[128][72];
    __shared__ __align__(16) _Float16 As2[128][72];
    __shared__ __align__(16) _Float16 Ws1[128][72];
    __shared__ __align__(16) _Float16 Ws2[128][72];
    __shared__ int ms[128];

    const int tid = threadIdx.x;
    const int m0 = blockIdx.y * 128, h0 = blockIdx.x * 32;
    const int l = tid & 63, wid = tid >> 6;
    const int wm = wid >> 1, wn = wid & 1;

    if (m_prev != nullptr && tid < 128) ms[tid] = m_prev[m0 + tid];

    f32x4 accM[2][4] = {};
    f32x4 accC[2][4] = {};

    for (int k0 = 0; k0 < H_; k0 += 64) {
        // stage: A = hx split rows m0..m0+127; W rows gate-major permuted
#pragma unroll
        for (int cc = 0; cc < 2; ++cc) {
            int c = tid + cc * 512;            // 0..1023 chunk id
            int r = c >> 3, q = (c & 7) << 3;  // row, col elem offset
            size_t ga = (size_t)(m0 + r) * H_ + k0 + q;
            *(uint4*)&As1[r][q] = *(const uint4*)(hx1 + ga);
            *(uint4*)&As2[r][q] = *(const uint4*)(hx2 + ga);
            // tile row r -> Whh row: g=(r>>4)&3, hh=r>>6, hl=r&15
            int wrow = ((r >> 4) & 3) * H_ + h0 + ((r >> 6) << 4) + (r & 15);
            size_t gw = (size_t)wrow * H_ + k0 + q;
            *(uint4*)&Ws1[r][q] = *(const uint4*)(W1 + gw);
            *(uint4*)&Ws2[r][q] = *(const uint4*)(W2 + gw);
        }
        __syncthreads();
        const int ac = (l >> 4) << 3;          // lane k-group offset
        const int arow = wm * 32 + (l & 15);
        const int brow = wn * 64 + (l & 15);
#pragma unroll
        for (int kc = 0; kc < 2; ++kc) {
            int ko = kc * 32 + ac;
            f16x8 b1[4], b2[4];
#pragma unroll
            for (int fn = 0; fn < 4; ++fn) {
                b1[fn] = *(const f16x8*)&Ws1[brow + fn * 16][ko];
                b2[fn] = *(const f16x8*)&Ws2[brow + fn * 16][ko];
            }
#pragma unroll
            for (int fm = 0; fm < 2; ++fm) {
                f16x8 a1 = *(const f16x8*)&As1[arow + fm * 16][ko];
                f16x8 a2 = *(const f16x8*)&As2[arow + fm * 16][ko];
#pragma unroll
                for (int fn = 0; fn < 4; ++fn) {
                    accM[fm][fn] = __builtin_amdgcn_mfma_f32_16x16x32_f16(
                        a1, b1[fn], accM[fm][fn], 0, 0, 0);
                    accC[fm][fn] = __builtin_amdgcn_mfma_f32_16x16x32_f16(
                        a1, b2[fn], accC[fm][fn], 0, 0, 0);
                    accC[fm][fn] = __builtin_amdgcn_mfma_f32_16x16x32_f16(
                        a2, b1[fn], accC[fm][fn], 0, 0, 0);
                }
            }
        }
        __syncthreads();
    }

    // ---- epilogue: each lane owns (h, all 4 gates) for 8 batch rows ----
    const int hl = l & 15;
    const int h  = h0 + wn * 16 + hl;
    const int rb = m0 + wm * 32 + ((l >> 4) << 2);
    float bs0 = bih[0 * H_ + h] + bhh[0 * H_ + h];
    float bs1 = bih[1 * H_ + h] + bhh[1 * H_ + h];
    float bs2 = bih[2 * H_ + h] + bhh[2 * H_ + h];
    float bs3 = bih[3 * H_ + h] + bhh[3 * H_ + h];
#pragma unroll
    for (int fm = 0; fm < 2; ++fm) {
#pragma unroll
        for (int rg = 0; rg < 4; ++rg) {
            int b = rb + fm * 16 + rg;
            float g0 = accM[fm][0][rg] + SPLIT_RS * accC[fm][0][rg] + bs0;
            float g1 = accM[fm][1][rg] + SPLIT_RS * accC[fm][1][rg] + bs1;
            float g2 = accM[fm][2][rg] + SPLIT_RS * accC[fm][2][rg] + bs2;
            float g3 = accM[fm][3][rg] + SPLIT_RS * accC[fm][3][rg] + bs3;
            if (m_prev != nullptr) {
                const float* Pr = P + (size_t)ms[b - m0] * H4_;
                g0 += Pr[0 * H_ + h]; g1 += Pr[1 * H_ + h];
                g2 += Pr[2 * H_ + h]; g3 += Pr[3 * H_ + h];
            }
            float ig = 1.f / (1.f + expf(-g0));
            float fg = 1.f / (1.f + expf(-g1));
            float gg = tanhf(g2);
            float og = 1.f / (1.f + expf(-g3));
            size_t off = (size_t)b * H_ + h;
            float cnew = fg * cx[off] + ig * gg;
            cx[off] = cnew;
            float hv = og * tanhf(cnew);
            _Float16 hh1 = (_Float16)hv;
            ho1[off] = hh1;
            ho2[off] = (_Float16)((hv - (float)hh1) * SPLIT_S);
            if (hof != nullptr) hof[off] = hv;
        }
    }
}

// ---------------------------------------------------------------------------
// MFMA split-fp16 GEMM for pre = hx @ h2t_W^T + b (dual write pre + logits).
// Block 64x128, 256 thr = 4 waves (2m x 2n), wave 32x64, BK=64.
// ---------------------------------------------------------------------------
__global__ __launch_bounds__(256) void gemm_pre_mfma(
    const _Float16* __restrict__ A1, const _Float16* __restrict__ A2, // [B][H]
    const _Float16* __restrict__ W1, const _Float16* __restrict__ W2, // [D][H]
    const float* __restrict__ bias,
    float* __restrict__ C,            // pre [B][D]
    float* __restrict__ C2, int ldc2) // logits slice (pre-offset by l*D)
{
    __shared__ __align__(16) _Float16 As1[64][72];
    __shared__ __align__(16) _Float16 As2[64][72];
    __shared__ __align__(16) _Float16 Ws1[128][72];
    __shared__ __align__(16) _Float16 Ws2[128][72];

    const int tid = threadIdx.x;
    const int m0 = blockIdx.y * 64, n0 = blockIdx.x * 128;
    const int l = tid & 63, wid = tid >> 6;
    const int wm = wid >> 1, wn = wid & 1;

    f32x4 accM[2][4] = {};
    f32x4 accC[2][4] = {};

    for (int k0 = 0; k0 < H_; k0 += 64) {
#pragma unroll
        for (int cc = 0; cc < 2; ++cc) {
            int c = tid + cc * 256;
            int r = c >> 3, q = (c & 7) << 3;
            size_t ga = (size_t)(m0 + r) * H_ + k0 + q;
            *(uint4*)&As1[r][q] = *(const uint4*)(A1 + ga);
            *(uint4*)&As2[r][q] = *(const uint4*)(A2 + ga);
        }
#pragma unroll
        for (int cc = 0; cc < 4; ++cc) {
            int c = tid + cc * 256;
            int r = c >> 3, q = (c & 7) << 3;
            size_t gw = (size_t)(n0 + r) * H_ + k0 + q;
            *(uint4*)&Ws1[r][q] = *(const uint4*)(W1 + gw);
            *(uint4*)&Ws2[r][q] = *(const uint4*)(W2 + gw);
        }
        __syncthreads();
        const int ac = (l >> 4) << 3;
        const int arow = wm * 32 + (l & 15);
        const int brow = wn * 64 + (l & 15);
#pragma unroll
        for (int kc = 0; kc < 2; ++kc) {
            int ko = kc * 32 + ac;
            f16x8 b1[4], b2[4];
#pragma unroll
            for (int fn = 0; fn < 4; ++fn) {
                b1[fn] = *(const f16x8*)&Ws1[brow + fn * 16][ko];
                b2[fn] = *(const f16x8*)&Ws2[brow + fn * 16][ko];
            }
#pragma unroll
            for (int fm = 0; fm < 2; ++fm) {
                f16x8 a1 = *(const f16x8*)&As1[arow + fm * 16][ko];
                f16x8 a2 = *(const f16x8*)&As2[arow + fm * 16][ko];
#pragma unroll
                for (int fn = 0; fn < 4; ++fn) {
                    accM[fm][fn] = __builtin_amdgcn_mfma_f32_16x16x32_f16(
                        a1, b1[fn], accM[fm][fn], 0, 0, 0);
                    accC[fm][fn] = __builtin_amdgcn_mfma_f32_16x16x32_f16(
                        a1, b2[fn], accC[fm][fn], 0, 0, 0);
                    accC[fm][fn] = __builtin_amdgcn_mfma_f32_16x16x32_f16(
                        a2, b1[fn], accC[fm][fn], 0, 0, 0);
                }
            }
        }
        __syncthreads();
    }

    const int hl = l & 15;
    const int rb = m0 + wm * 32 + ((l >> 4) << 2);
#pragma unroll
    for (int fn = 0; fn < 4; ++fn) {
        int d = n0 + wn * 64 + fn * 16 + hl;
        float bv = bias[d];
#pragma unroll
        for (int fm = 0; fm < 2; ++fm)
#pragma unroll
            for (int rg = 0; rg < 4; ++rg) {
                int b = rb + fm * 16 + rg;
                float v = accM[fm][fn][rg] + SPLIT_RS * accC[fm][fn][rg] + bv;
                C[(size_t)b * D_ + d] = v;
                C2[(size_t)b * ldc2 + d] = v;
            }
    }
}

// ---------------------------------------------------------------------------
// argmax over D of pre[b,:] + gumbel[l,b,:]; one wave per row.
// ---------------------------------------------------------------------------
__global__ __launch_bounds__(256) void argmax_step(
    const float* __restrict__ pre, const float* __restrict__ gum,
    float* __restrict__ onehot, float* __restrict__ messages,
    int* __restrict__ m_out, int l)
{
    const int wave = threadIdx.x >> 6, lane = threadIdx.x & 63;
    const int b = blockIdx.x * 4 + wave;
    const float* pr = pre + (long long)b * D_;
    const float* gr = gum + (long long)b * D_;
    float best = -INFINITY; int bi = 0;
#pragma unroll
    for (int j = 0; j < D_ / 64; ++j) {
        int idx = lane + j * 64;
        float v = pr[idx] + gr[idx];
        if (v > best) { best = v; bi = idx; }
    }
#pragma unroll
    for (int off = 32; off > 0; off >>= 1) {
        float ov = __shfl_down(best, off);
        int   oi = __shfl_down(bi, off);
        if (ov > best || (ov == best && oi < bi)) { best = ov; bi = oi; }
    }
    if (lane == 0) {
        m_out[b] = bi;
        messages[(long long)b * L_ + l] = (float)bi;
        onehot[((long long)b * L_ + l) * D_ + bi] = 1.0f;
    }
}

// t2h_emb[d, h] = t2h_W[h, d] + t2h_b[h]
__global__ __launch_bounds__(256) void build_emb(
    const float* __restrict__ t2h_W, const float* __restrict__ t2h_b,
    float* __restrict__ emb)
{
    int idx = blockIdx.x * 256 + threadIdx.x;
    int d = idx >> 9, h = idx & (H_ - 1);
    emb[idx] = t2h_W[(long long)h * D_ + d] + t2h_b[h];
}

// ---------------------------------------------------------------------------
extern "C" void kernel_launch(void* const* d_in, const int* in_sizes, int n_in,
                              void* d_out, int out_size, void* d_ws, size_t ws_size,
                              hipStream_t stream)
{
    (void)in_sizes; (void)n_in; (void)out_size; (void)ws_size;
    const float* x       = (const float*)d_in[0];
    const float* gumbel  = (const float*)d_in[1];
    const float* in_W    = (const float*)d_in[2];
    const float* in_b    = (const float*)d_in[3];
    const float* out_W   = (const float*)d_in[4];
    const float* out_b   = (const float*)d_in[5];
    const float* enc_Wih = (const float*)d_in[6];
    const float* enc_Whh = (const float*)d_in[7];
    const float* enc_bih = (const float*)d_in[8];
    const float* enc_bhh = (const float*)d_in[9];
    const float* dec_Wih = (const float*)d_in[10];
    const float* dec_Whh = (const float*)d_in[11];
    const float* dec_bih = (const float*)d_in[12];
    const float* dec_bhh = (const float*)d_in[13];
    const float* h2t_W   = (const float*)d_in[14];
    const float* h2t_b   = (const float*)d_in[15];
    const float* t2h_W   = (const float*)d_in[16];
    const float* t2h_b   = (const float*)d_in[17];

    float* out      = (float*)d_out;
    float* recon    = out;                                  // [B,O]
    float* onehot   = out + (size_t)B_ * O_;                // [B,L,D]
    float* logits   = onehot + (size_t)B_ * L_ * D_;        // [B,L,D]
    float* messages = logits + (size_t)B_ * L_ * D_;        // [B,L]

    float* ws    = (float*)d_ws;
    float* cx    = ws;                                      // [B,H]
    float* pre   = cx + (size_t)B_ * H_;                    // [B,D]
    float* emb   = pre + (size_t)B_ * D_;                   // [D,H]
    float* P_enc = emb + (size_t)D_ * H_;                   // [D,4H]
    float* P_dec = P_enc + (size_t)D_ * H4_;                // [D,4H]
    float* hxf   = P_dec + (size_t)D_ * H4_;                // [B,H] fp32 final hx
    int*   m_all = (int*)(hxf + (size_t)B_ * H_);           // [L,B]
    _Float16* fb   = (_Float16*)(m_all + (size_t)L_ * B_);
    _Float16* hxA1 = fb;  fb += (size_t)B_ * H_;
    _Float16* hxA2 = fb;  fb += (size_t)B_ * H_;
    _Float16* hxB1 = fb;  fb += (size_t)B_ * H_;
    _Float16* hxB2 = fb;  fb += (size_t)B_ * H_;
    _Float16* encW1 = fb; fb += (size_t)H4_ * H_;
    _Float16* encW2 = fb; fb += (size_t)H4_ * H_;
    _Float16* decW1 = fb; fb += (size_t)H4_ * H_;
    _Float16* decW2 = fb; fb += (size_t)H4_ * H_;
    _Float16* h2t1  = fb; fb += (size_t)D_ * H_;
    _Float16* h2t2  = fb;

    const dim3 blk256(256);

    // zero hxA split pair (contiguous) and one_hot
    hipMemsetAsync(hxA1, 0, (size_t)B_ * H_ * 4, stream);
    hipMemsetAsync(onehot, 0, (size_t)B_ * L_ * D_ * sizeof(float), stream);

    // weight splits (one-time)
    split_f16<<<dim3((H4_ * H_ / 4) / 256), blk256, 0, stream>>>(
        enc_Whh, encW1, encW2, H4_ * H_ / 4);
    split_f16<<<dim3((H4_ * H_ / 4) / 256), blk256, 0, stream>>>(
        dec_Whh, decW1, decW2, H4_ * H_ / 4);
    split_f16<<<dim3((D_ * H_ / 4) / 256), blk256, 0, stream>>>(
        h2t_W, h2t1, h2t2, D_ * H_ / 4);

    // cx0 (encoder initial cell state) = x @ in_W^T + in_b  (fp32)
    gemm_atb<<<dim3(H_ / 64, B_ / 64), blk256, 0, stream>>>(
        x, in_W, in_b, cx, H_, nullptr, 0, B_, H_, I_);

    // one-hot decode table and the two precomputed gather tables (fp32)
    build_emb<<<dim3((D_ * H_) / 256), blk256, 0, stream>>>(t2h_W, t2h_b, emb);
    gemm_atb<<<dim3(H4_ / 64, D_ / 64), blk256, 0, stream>>>(
        emb, enc_Wih, nullptr, P_enc, H4_, nullptr, 0, D_, H4_, H_);
    gemm_atb<<<dim3(H4_ / 64, D_ / 64), blk256, 0, stream>>>(
        emb, dec_Wih, nullptr, P_dec, H4_, nullptr, 0, D_, H4_, H_);

    // ---------------- encoder ----------------
    _Float16 *c1 = hxA1, *c2 = hxA2, *n1 = hxB1, *n2 = hxB2;
    for (int l = 0; l < L_; ++l) {
        lstm_step_mfma<<<dim3(H_ / 32, B_ / 128), dim3(512), 0, stream>>>(
            c1, c2, cx, encW1, encW2, P_enc,
            (l == 0) ? nullptr : (m_all + (size_t)(l - 1) * B_),
            enc_bih, enc_bhh, n1, n2, nullptr);
        { _Float16* t = c1; c1 = n1; n1 = t; t = c2; c2 = n2; n2 = t; }
        gemm_pre_mfma<<<dim3(D_ / 128, B_ / 64), blk256, 0, stream>>>(
            c1, c2, h2t1, h2t2, h2t_b, pre,
            logits + (size_t)l * D_, L_ * D_);
        argmax_step<<<dim3(B_ / 4), blk256, 0, stream>>>(
            pre, gumbel + (size_t)l * B_ * D_, onehot, messages,
            m_all + (size_t)l * B_, l);
    }

    // ---------------- decoder ----------------
    // after 32 swaps c1/c2 == hxA pair again; zero it + cx
    hipMemsetAsync(c1, 0, (size_t)B_ * H_ * 2, stream);
    hipMemsetAsync(c2, 0, (size_t)B_ * H_ * 2, stream);
    hipMemsetAsync(cx, 0, (size_t)B_ * H_ * sizeof(float), stream);
    for (int l = 0; l < L_; ++l) {
        lstm_step_mfma<<<dim3(H_ / 32, B_ / 128), dim3(512), 0, stream>>>(
            c1, c2, cx, decW1, decW2, P_dec, m_all + (size_t)l * B_,
            dec_bih, dec_bhh, n1, n2, (l == L_ - 1) ? hxf : nullptr);
        { _Float16* t = c1; c1 = n1; n1 = t; t = c2; c2 = n2; n2 = t; }
    }

    // recon = hx_final @ out_W^T + out_b  (fp32)
    gemm_atb<<<dim3(O_ / 64, B_ / 64), blk256, 0, stream>>>(
        hxf, out_W, out_b, recon, O_, nullptr, 0, B_, O_, H_);
}

// Round 2
// 3169.043 us; speedup vs baseline: 2.0114x; 1.0125x over previous
//
#include <hip/hip_runtime.h>
#include <math.h>

#define B_  2048
#define I_  512
#define H_  512
#define L_  32
#define D_  1024
#define O_  512
#define H4_ 2048
#define KC  32

typedef _Float16 f16x8 __attribute__((ext_vector_type(8)));
typedef _Float16 f16x4 __attribute__((ext_vector_type(4)));
typedef float    f32x4 __attribute__((ext_vector_type(4)));

#define SPLIT_S  1024.0f
#define SPLIT_RS 0.0009765625f   /* 1/1024 */

// async global->LDS, 16B per lane; LDS dest = wave-uniform base + lane*16
__device__ __forceinline__ void gload16(const _Float16* g, _Float16* l) {
    __builtin_amdgcn_global_load_lds(
        (const __attribute__((address_space(1))) void*)g,
        (__attribute__((address_space(3))) void*)l, 16, 0, 0);
}

// swizzled fragment read: LDS chunk c holds global chunk c^(row&7)
__device__ __forceinline__ f16x8 lds_frag(const _Float16* base, int row, int ko) {
    int off = row * 64 + ((((ko >> 3) ^ (row & 7))) << 3);
    return *(const f16x8*)(base + off);
}

// ---------------------------------------------------------------------------
// Generic fp32 GEMM (kept for one-time GEMMs: cx0, P_enc, P_dec, recon).
// ---------------------------------------------------------------------------
__global__ __launch_bounds__(256) void gemm_atb(
    const float* __restrict__ A, const float* __restrict__ W,
    const float* __restrict__ bias, float* __restrict__ C, int ldc,
    float* __restrict__ C2, int ldc2,
    int M, int N, int K)
{
    __shared__ __align__(16) float As[KC][68];
    __shared__ __align__(16) float Ws[KC][68];
    const int tx = threadIdx.x & 15, ty = threadIdx.x >> 4;
    const int m0 = blockIdx.y * 64, n0 = blockIdx.x * 64;
    float acc[4][4] = {};

    for (int k0 = 0; k0 < K; k0 += KC) {
#pragma unroll
        for (int p = 0; p < 2; ++p) {
            int q = threadIdx.x + 256 * p;
            int r = q >> 3, c = q & 7;
            float4 va = *reinterpret_cast<const float4*>(
                &A[(long long)(m0 + r) * K + k0 + c * 4]);
            As[c * 4 + 0][r] = va.x; As[c * 4 + 1][r] = va.y;
            As[c * 4 + 2][r] = va.z; As[c * 4 + 3][r] = va.w;
            float4 vw = *reinterpret_cast<const float4*>(
                &W[(long long)(n0 + r) * K + k0 + c * 4]);
            Ws[c * 4 + 0][r] = vw.x; Ws[c * 4 + 1][r] = vw.y;
            Ws[c * 4 + 2][r] = vw.z; Ws[c * 4 + 3][r] = vw.w;
        }
        __syncthreads();
#pragma unroll
        for (int kk = 0; kk < KC; ++kk) {
            float4 a = *reinterpret_cast<const float4*>(&As[kk][ty * 4]);
            float4 w = *reinterpret_cast<const float4*>(&Ws[kk][tx * 4]);
            float av[4] = {a.x, a.y, a.z, a.w};
            float wv[4] = {w.x, w.y, w.z, w.w};
#pragma unroll
            for (int i = 0; i < 4; ++i)
#pragma unroll
                for (int j = 0; j < 4; ++j)
                    acc[i][j] = fmaf(av[i], wv[j], acc[i][j]);
        }
        __syncthreads();
    }

#pragma unroll
    for (int i = 0; i < 4; ++i) {
        int m = m0 + ty * 4 + i;
        int n = n0 + tx * 4;
        float4 out;
        out.x = acc[i][0]; out.y = acc[i][1]; out.z = acc[i][2]; out.w = acc[i][3];
        if (bias) {
            out.x += bias[n + 0]; out.y += bias[n + 1];
            out.z += bias[n + 2]; out.w += bias[n + 3];
        }
        *reinterpret_cast<float4*>(&C[(long long)m * ldc + n]) = out;
        if (C2)
            *reinterpret_cast<float4*>(&C2[(long long)m * ldc2 + n]) = out;
    }
}

// ---------------------------------------------------------------------------
// Split fp32 -> scaled fp16 pair:  x ~= x1 + x2/1024  (error ~2^-22 |x|).
// ---------------------------------------------------------------------------
__global__ __launch_bounds__(256) void split_f16(
    const float* __restrict__ src, _Float16* __restrict__ d1,
    _Float16* __restrict__ d2, int n4)
{
    int i = blockIdx.x * 256 + threadIdx.x;
    if (i >= n4) return;
    float4 v = reinterpret_cast<const float4*>(src)[i];
    float vv[4] = {v.x, v.y, v.z, v.w};
    f16x4 o1, o2;
#pragma unroll
    for (int j = 0; j < 4; ++j) {
        _Float16 hh = (_Float16)vv[j];
        o1[j] = hh;
        o2[j] = (_Float16)((vv[j] - (float)hh) * SPLIT_S);
    }
    *reinterpret_cast<f16x4*>(d1 + 4 * i) = o1;
    *reinterpret_cast<f16x4*>(d2 + 4 * i) = o2;
}

// ---------------------------------------------------------------------------
// Fused MFMA LSTM step.  Linear LDS [128][64] per array, staged via
// global_load_lds (16B) with XOR-swizzled source chunks; fragments read
// with the matching XOR.  512 thr = 8 waves (4m x 2n), wave tile 32x64,
// BK=64, 16x16x32 f16 MFMA, split-fp16 dual accumulators.
// ---------------------------------------------------------------------------
__global__ __launch_bounds__(512) void lstm_step_mfma(
    const _Float16* __restrict__ hx1, const _Float16* __restrict__ hx2,
    float* __restrict__ cx,
    const _Float16* __restrict__ W1, const _Float16* __restrict__ W2, // [4H][H]
    const float* __restrict__ P,      // [D][4H] gather table (fp32)
    const int* __restrict__ m_prev,   // [B] or nullptr
    const float* __restrict__ bih, const float* __restrict__ bhh,
    _Float16* __restrict__ ho1, _Float16* __restrict__ ho2,
    float* __restrict__ hof)          // fp32 hx out (nullptr to skip)
{
    __shared__ __align__(16) _Float16 As1[128 * 64];
    __shared__ __align__(16) _Float16 As2[128 * 64];
    __shared__ __align__(16) _Float16 Ws1[128 * 64];
    __shared__ __align__(16) _Float16 Ws2[128 * 64];
    __shared__ int ms[128];

    const int tid = threadIdx.x;
    const int m0 = blockIdx.y * 128, h0 = blockIdx.x * 32;
    const int l = tid & 63, wid = tid >> 6;
    const int wm = wid >> 1, wn = wid & 1;

    if (m_prev != nullptr && tid < 128) ms[tid] = m_prev[m0 + tid];

    f32x4 accM[2][4] = {};
    f32x4 accC[2][4] = {};

    for (int k0 = 0; k0 < H_; k0 += 64) {
        // stage 4 x 16KB tiles; each wave owns segments wid and wid+8
        // (1 segment = 8 rows = 1KB). source chunk = (lane&7) ^ (lane>>3).
#pragma unroll
        for (int s = 0; s < 2; ++s) {
            int seg = wid + s * 8;
            int r   = seg * 8 + (l >> 3);
            int jsw = ((l & 7) ^ (l >> 3)) << 3;    // halfs within row
            size_t ga = (size_t)(m0 + r) * H_ + k0 + jsw;
            gload16(hx1 + ga, &As1[seg * 512]);
            gload16(hx2 + ga, &As2[seg * 512]);
            int wrow = ((r >> 4) & 3) * H_ + h0 + ((r >> 6) << 4) + (r & 15);
            size_t gw = (size_t)wrow * H_ + k0 + jsw;
            gload16(W1 + gw, &Ws1[seg * 512]);
            gload16(W2 + gw, &Ws2[seg * 512]);
        }
        __syncthreads();
        const int ac = (l >> 4) << 3;
        const int arow = wm * 32 + (l & 15);
        const int brow = wn * 64 + (l & 15);
#pragma unroll
        for (int kc = 0; kc < 2; ++kc) {
            int ko = kc * 32 + ac;
            f16x8 b1[4], b2[4];
#pragma unroll
            for (int fn = 0; fn < 4; ++fn) {
                b1[fn] = lds_frag(Ws1, brow + fn * 16, ko);
                b2[fn] = lds_frag(Ws2, brow + fn * 16, ko);
            }
#pragma unroll
            for (int fm = 0; fm < 2; ++fm) {
                f16x8 a1 = lds_frag(As1, arow + fm * 16, ko);
                f16x8 a2 = lds_frag(As2, arow + fm * 16, ko);
#pragma unroll
                for (int fn = 0; fn < 4; ++fn) {
                    accM[fm][fn] = __builtin_amdgcn_mfma_f32_16x16x32_f16(
                        a1, b1[fn], accM[fm][fn], 0, 0, 0);
                    accC[fm][fn] = __builtin_amdgcn_mfma_f32_16x16x32_f16(
                        a1, b2[fn], accC[fm][fn], 0, 0, 0);
                    accC[fm][fn] = __builtin_amdgcn_mfma_f32_16x16x32_f16(
                        a2, b1[fn], accC[fm][fn], 0, 0, 0);
                }
            }
        }
        __syncthreads();
    }

    // ---- epilogue: each lane owns (h, all 4 gates) for 8 batch rows ----
    const int hl = l & 15;
    const int h  = h0 + wn * 16 + hl;
    const int rb = m0 + wm * 32 + ((l >> 4) << 2);
    float bs0 = bih[0 * H_ + h] + bhh[0 * H_ + h];
    float bs1 = bih[1 * H_ + h] + bhh[1 * H_ + h];
    float bs2 = bih[2 * H_ + h] + bhh[2 * H_ + h];
    float bs3 = bih[3 * H_ + h] + bhh[3 * H_ + h];
#pragma unroll
    for (int fm = 0; fm < 2; ++fm) {
#pragma unroll
        for (int rg = 0; rg < 4; ++rg) {
            int b = rb + fm * 16 + rg;
            float g0 = accM[fm][0][rg] + SPLIT_RS * accC[fm][0][rg] + bs0;
            float g1 = accM[fm][1][rg] + SPLIT_RS * accC[fm][1][rg] + bs1;
            float g2 = accM[fm][2][rg] + SPLIT_RS * accC[fm][2][rg] + bs2;
            float g3 = accM[fm][3][rg] + SPLIT_RS * accC[fm][3][rg] + bs3;
            if (m_prev != nullptr) {
                const float* Pr = P + (size_t)ms[b - m0] * H4_;
                g0 += Pr[0 * H_ + h]; g1 += Pr[1 * H_ + h];
                g2 += Pr[2 * H_ + h]; g3 += Pr[3 * H_ + h];
            }
            float ig = 1.f / (1.f + expf(-g0));
            float fg = 1.f / (1.f + expf(-g1));
            float gg = tanhf(g2);
            float og = 1.f / (1.f + expf(-g3));
            size_t off = (size_t)b * H_ + h;
            float cnew = fg * cx[off] + ig * gg;
            cx[off] = cnew;
            float hv = og * tanhf(cnew);
            _Float16 hh1 = (_Float16)hv;
            ho1[off] = hh1;
            ho2[off] = (_Float16)((hv - (float)hh1) * SPLIT_S);
            if (hof != nullptr) hof[off] = hv;
        }
    }
}

// ---------------------------------------------------------------------------
// MFMA split-fp16 pre-GEMM with FUSED argmax partials.
//   logits[b,d] = hx@h2t^T + b  (written);  per-block argmax partial of
//   logits + gumbel over its 128 cols -> pbest/pidx[b][blockIdx.x].
// Block 64x128, 256 thr = 4 waves (2m x 2n), BK=64, gload_lds staging.
// ---------------------------------------------------------------------------
__global__ __launch_bounds__(256) void gemm_pre_fused(
    const _Float16* __restrict__ A1, const _Float16* __restrict__ A2, // [B][H]
    const _Float16* __restrict__ W1, const _Float16* __restrict__ W2, // [D][H]
    const float* __restrict__ bias,
    float* __restrict__ C2, int ldc2,   // logits slice (offset by l*D)
    const float* __restrict__ gum,      // gumbel + l*B*D  -> [B][D]
    float* __restrict__ pbest, int* __restrict__ pidx)  // [B][8]
{
    __shared__ __align__(16) _Float16 As1[64 * 64];
    __shared__ __align__(16) _Float16 As2[64 * 64];
    __shared__ __align__(16) _Float16 Ws1[128 * 64];
    __shared__ __align__(16) _Float16 Ws2[128 * 64];
    __shared__ float cb[2][64];
    __shared__ int   ci[2][64];

    const int tid = threadIdx.x;
    const int m0 = blockIdx.y * 64, n0 = blockIdx.x * 128;
    const int l = tid & 63, wid = tid >> 6;
    const int wm = wid >> 1, wn = wid & 1;

    f32x4 accM[2][4] = {};
    f32x4 accC[2][4] = {};

    for (int k0 = 0; k0 < H_; k0 += 64) {
#pragma unroll
        for (int s = 0; s < 2; ++s) {           // A: 8 segments over 4 waves
            int seg = wid + s * 4;
            int r   = seg * 8 + (l >> 3);
            int jsw = ((l & 7) ^ (l >> 3)) << 3;
            size_t ga = (size_t)(m0 + r) * H_ + k0 + jsw;
            gload16(A1 + ga, &As1[seg * 512]);
            gload16(A2 + ga, &As2[seg * 512]);
        }
#pragma unroll
        for (int s = 0; s < 4; ++s) {           // W: 16 segments over 4 waves
            int seg = wid + s * 4;
            int r   = seg * 8 + (l >> 3);
            int jsw = ((l & 7) ^ (l >> 3)) << 3;
            size_t gw = (size_t)(n0 + r) * H_ + k0 + jsw;
            gload16(W1 + gw, &Ws1[seg * 512]);
            gload16(W2 + gw, &Ws2[seg * 512]);
        }
        __syncthreads();
        const int ac = (l >> 4) << 3;
        const int arow = wm * 32 + (l & 15);
        const int brow = wn * 64 + (l & 15);
#pragma unroll
        for (int kc = 0; kc < 2; ++kc) {
            int ko = kc * 32 + ac;
            f16x8 b1[4], b2[4];
#pragma unroll
            for (int fn = 0; fn < 4; ++fn) {
                b1[fn] = lds_frag(Ws1, brow + fn * 16, ko);
                b2[fn] = lds_frag(Ws2, brow + fn * 16, ko);
            }
#pragma unroll
            for (int fm = 0; fm < 2; ++fm) {
                f16x8 a1 = lds_frag(As1, arow + fm * 16, ko);
                f16x8 a2 = lds_frag(As2, arow + fm * 16, ko);
#pragma unroll
                for (int fn = 0; fn < 4; ++fn) {
                    accM[fm][fn] = __builtin_amdgcn_mfma_f32_16x16x32_f16(
                        a1, b1[fn], accM[fm][fn], 0, 0, 0);
                    accC[fm][fn] = __builtin_amdgcn_mfma_f32_16x16x32_f16(
                        a1, b2[fn], accC[fm][fn], 0, 0, 0);
                    accC[fm][fn] = __builtin_amdgcn_mfma_f32_16x16x32_f16(
                        a2, b1[fn], accC[fm][fn], 0, 0, 0);
                }
            }
        }
        __syncthreads();
    }

    // ---- epilogue: write logits; fold gumbel; per-block argmax partial ----
    const int hl = l & 15;
    const int g4 = l >> 4;
    const int rb = m0 + wm * 32 + (g4 << 2);
    float vbest[2][4]; int vidx[2][4];
#pragma unroll
    for (int fm = 0; fm < 2; ++fm)
#pragma unroll
        for (int rg = 0; rg < 4; ++rg) { vbest[fm][rg] = -INFINITY; vidx[fm][rg] = 0; }

#pragma unroll
    for (int fn = 0; fn < 4; ++fn) {
        int d = n0 + wn * 64 + fn * 16 + hl;
        float bv = bias[d];
#pragma unroll
        for (int fm = 0; fm < 2; ++fm)
#pragma unroll
            for (int rg = 0; rg < 4; ++rg) {
                int b = rb + fm * 16 + rg;
                float v = accM[fm][fn][rg] + SPLIT_RS * accC[fm][fn][rg] + bv;
                C2[(size_t)b * ldc2 + d] = v;
                float t = v + gum[(size_t)b * D_ + d];
                if (t > vbest[fm][rg]) { vbest[fm][rg] = t; vidx[fm][rg] = d; }
            }
    }

    // butterfly over the 16 hl lanes (d ascending with fn; ties keep low d)
#pragma unroll
    for (int off = 1; off < 16; off <<= 1) {
#pragma unroll
        for (int fm = 0; fm < 2; ++fm)
#pragma unroll
            for (int rg = 0; rg < 4; ++rg) {
                float ov = __shfl_xor(vbest[fm][rg], off);
                int   oi = __shfl_xor(vidx[fm][rg], off);
                if (ov > vbest[fm][rg] ||
                    (ov == vbest[fm][rg] && oi < vidx[fm][rg])) {
                    vbest[fm][rg] = ov; vidx[fm][rg] = oi;
                }
            }
    }
    if (hl == 0) {
#pragma unroll
        for (int fm = 0; fm < 2; ++fm)
#pragma unroll
            for (int rg = 0; rg < 4; ++rg) {
                int rl = wm * 32 + fm * 16 + (g4 << 2) + rg;
                cb[wn][rl] = vbest[fm][rg];
                ci[wn][rl] = vidx[fm][rg];
            }
    }
    __syncthreads();
    if (tid < 64) {
        float b0 = cb[0][tid]; int i0 = ci[0][tid];
        float b1v = cb[1][tid]; int i1 = ci[1][tid];
        if (b1v > b0 || (b1v == b0 && i1 < i0)) { b0 = b1v; i0 = i1; }
        pbest[(size_t)(m0 + tid) * 8 + blockIdx.x] = b0;
        pidx [(size_t)(m0 + tid) * 8 + blockIdx.x] = i0;
    }
}

// final reduce of the 8 per-block partials; writes messages/onehot/m_out
__global__ __launch_bounds__(256) void argmax_fin(
    const float* __restrict__ pbest, const int* __restrict__ pidx,
    float* __restrict__ onehot, float* __restrict__ messages,
    int* __restrict__ m_out, int l)
{
    int b = blockIdx.x * 256 + threadIdx.x;
    float best = -INFINITY; int bi = 0;
#pragma unroll
    for (int j = 0; j < 8; ++j) {
        float v = pbest[(size_t)b * 8 + j];
        int   i = pidx [(size_t)b * 8 + j];
        if (v > best || (v == best && i < bi)) { best = v; bi = i; }
    }
    m_out[b] = bi;
    messages[(size_t)b * L_ + l] = (float)bi;
    onehot[((size_t)b * L_ + l) * D_ + bi] = 1.0f;
}

// t2h_emb[d, h] = t2h_W[h, d] + t2h_b[h]
__global__ __launch_bounds__(256) void build_emb(
    const float* __restrict__ t2h_W, const float* __restrict__ t2h_b,
    float* __restrict__ emb)
{
    int idx = blockIdx.x * 256 + threadIdx.x;
    int d = idx >> 9, h = idx & (H_ - 1);
    emb[idx] = t2h_W[(long long)h * D_ + d] + t2h_b[h];
}

// ---------------------------------------------------------------------------
extern "C" void kernel_launch(void* const* d_in, const int* in_sizes, int n_in,
                              void* d_out, int out_size, void* d_ws, size_t ws_size,
                              hipStream_t stream)
{
    (void)in_sizes; (void)n_in; (void)out_size; (void)ws_size;
    const float* x       = (const float*)d_in[0];
    const float* gumbel  = (const float*)d_in[1];
    const float* in_W    = (const float*)d_in[2];
    const float* in_b    = (const float*)d_in[3];
    const float* out_W   = (const float*)d_in[4];
    const float* out_b   = (const float*)d_in[5];
    const float* enc_Wih = (const float*)d_in[6];
    const float* enc_Whh = (const float*)d_in[7];
    const float* enc_bih = (const float*)d_in[8];
    const float* enc_bhh = (const float*)d_in[9];
    const float* dec_Wih = (const float*)d_in[10];
    const float* dec_Whh = (const float*)d_in[11];
    const float* dec_bih = (const float*)d_in[12];
    const float* dec_bhh = (const float*)d_in[13];
    const float* h2t_W   = (const float*)d_in[14];
    const float* h2t_b   = (const float*)d_in[15];
    const float* t2h_W   = (const float*)d_in[16];
    const float* t2h_b   = (const float*)d_in[17];

    float* out      = (float*)d_out;
    float* recon    = out;                                  // [B,O]
    float* onehot   = out + (size_t)B_ * O_;                // [B,L,D]
    float* logits   = onehot + (size_t)B_ * L_ * D_;        // [B,L,D]
    float* messages = logits + (size_t)B_ * L_ * D_;        // [B,L]

    float* ws    = (float*)d_ws;
    float* cx    = ws;                                      // [B,H]
    float* emb   = cx + (size_t)B_ * H_;                    // [D,H]
    float* P_enc = emb + (size_t)D_ * H_;                   // [D,4H]
    float* P_dec = P_enc + (size_t)D_ * H4_;                // [D,4H]
    float* hxf   = P_dec + (size_t)D_ * H4_;                // [B,H]
    float* pbest = hxf + (size_t)B_ * H_;                   // [B,8]
    int*   pidx  = (int*)(pbest + (size_t)B_ * 8);          // [B,8]
    int*   m_all = pidx + (size_t)B_ * 8;                   // [L,B]
    _Float16* fb   = (_Float16*)(m_all + (size_t)L_ * B_);
    _Float16* hxA1 = fb;  fb += (size_t)B_ * H_;
    _Float16* hxA2 = fb;  fb += (size_t)B_ * H_;
    _Float16* hxB1 = fb;  fb += (size_t)B_ * H_;
    _Float16* hxB2 = fb;  fb += (size_t)B_ * H_;
    _Float16* encW1 = fb; fb += (size_t)H4_ * H_;
    _Float16* encW2 = fb; fb += (size_t)H4_ * H_;
    _Float16* decW1 = fb; fb += (size_t)H4_ * H_;
    _Float16* decW2 = fb; fb += (size_t)H4_ * H_;
    _Float16* h2t1  = fb; fb += (size_t)D_ * H_;
    _Float16* h2t2  = fb;

    const dim3 blk256(256);

    hipMemsetAsync(hxA1, 0, (size_t)B_ * H_ * 4, stream);
    hipMemsetAsync(onehot, 0, (size_t)B_ * L_ * D_ * sizeof(float), stream);

    // weight splits (one-time)
    split_f16<<<dim3((H4_ * H_ / 4) / 256), blk256, 0, stream>>>(
        enc_Whh, encW1, encW2, H4_ * H_ / 4);
    split_f16<<<dim3((H4_ * H_ / 4) / 256), blk256, 0, stream>>>(
        dec_Whh, decW1, decW2, H4_ * H_ / 4);
    split_f16<<<dim3((D_ * H_ / 4) / 256), blk256, 0, stream>>>(
        h2t_W, h2t1, h2t2, D_ * H_ / 4);

    // cx0 (encoder initial cell state) = x @ in_W^T + in_b  (fp32)
    gemm_atb<<<dim3(H_ / 64, B_ / 64), blk256, 0, stream>>>(
        x, in_W, in_b, cx, H_, nullptr, 0, B_, H_, I_);

    // one-hot decode table and the two precomputed gather tables (fp32)
    build_emb<<<dim3((D_ * H_) / 256), blk256, 0, stream>>>(t2h_W, t2h_b, emb);
    gemm_atb<<<dim3(H4_ / 64, D_ / 64), blk256, 0, stream>>>(
        emb, enc_Wih, nullptr, P_enc, H4_, nullptr, 0, D_, H4_, H_);
    gemm_atb<<<dim3(H4_ / 64, D_ / 64), blk256, 0, stream>>>(
        emb, dec_Wih, nullptr, P_dec, H4_, nullptr, 0, D_, H4_, H_);

    // ---------------- encoder ----------------
    _Float16 *c1 = hxA1, *c2 = hxA2, *n1 = hxB1, *n2 = hxB2;
    for (int l = 0; l < L_; ++l) {
        lstm_step_mfma<<<dim3(H_ / 32, B_ / 128), dim3(512), 0, stream>>>(
            c1, c2, cx, encW1, encW2, P_enc,
            (l == 0) ? nullptr : (m_all + (size_t)(l - 1) * B_),
            enc_bih, enc_bhh, n1, n2, nullptr);
        { _Float16* t = c1; c1 = n1; n1 = t; t = c2; c2 = n2; n2 = t; }
        gemm_pre_fused<<<dim3(D_ / 128, B_ / 64), blk256, 0, stream>>>(
            c1, c2, h2t1, h2t2, h2t_b,
            logits + (size_t)l * D_, L_ * D_,
            gumbel + (size_t)l * B_ * D_, pbest, pidx);
        argmax_fin<<<dim3(B_ / 256), blk256, 0, stream>>>(
            pbest, pidx, onehot, messages, m_all + (size_t)l * B_, l);
    }

    // ---------------- decoder ----------------
    hipMemsetAsync(c1, 0, (size_t)B_ * H_ * 2, stream);
    hipMemsetAsync(c2, 0, (size_t)B_ * H_ * 2, stream);
    hipMemsetAsync(cx, 0, (size_t)B_ * H_ * sizeof(float), stream);
    for (int l = 0; l < L_; ++l) {
        lstm_step_mfma<<<dim3(H_ / 32, B_ / 128), dim3(512), 0, stream>>>(
            c1, c2, cx, decW1, decW2, P_dec, m_all + (size_t)l * B_,
            dec_bih, dec_bhh, n1, n2, (l == L_ - 1) ? hxf : nullptr);
        { _Float16* t = c1; c1 = n1; n1 = t; t = c2; c2 = n2; n2 = t; }
    }

    // recon = hx_final @ out_W^T + out_b  (fp32)
    gemm_atb<<<dim3(O_ / 64, B_ / 64), blk256, 0, stream>>>(
        hxf, out_W, out_b, recon, O_, nullptr, 0, B_, O_, H_);
}